// Round 1
// baseline (24884.927 us; speedup 1.0000x reference)
//
#include <hip/hip_runtime.h>
#include <hip/hip_cooperative_groups.h>

namespace cg = cooperative_groups;

#define BETA 0.125f
#define V_TH (-15.0f)
#define A_R 1.0f
#define A_D 5.0f

__device__ __forceinline__ float wave_reduce(float v) {
    #pragma unroll
    for (int off = 32; off > 0; off >>= 1) v += __shfl_xor(v, off, 64);
    return v;
}

__global__ void k_mean(const float* __restrict__ in, int n, float* __restrict__ out) {
    __shared__ float partial[4];
    int tid = threadIdx.x;
    float acc = 0.f;
    for (int i = tid; i < n; i += 256) acc += in[i];
    acc = wave_reduce(acc);
    int wid = tid >> 6;
    if ((tid & 63) == 0) partial[wid] = acc;
    __syncthreads();
    if (tid == 0) out[0] = (partial[0] + partial[1] + partial[2] + partial[3]) / (float)n;
}

__global__ void k_init(const float* __restrict__ input_V, const float* __restrict__ E_syn,
                       const float* __restrict__ avg, int in_len, int size,
                       float* __restrict__ V, float* __restrict__ s, float* __restrict__ sE) {
    int i = blockIdx.x * blockDim.x + threadIdx.x;
    if (i >= size) return;
    float v = (i < in_len) ? input_V[i] : avg[0];
    float sig = 1.f / (1.f + expf(-(BETA * (v - V_TH))));
    float s0 = A_R * sig / (A_R * sig + A_D);
    V[i] = v;
    s[i] = s0;
    sE[i] = s0 * E_syn[i];
}

__global__ void k_cogap(const float* __restrict__ G_gap, int size, float* __restrict__ co_gap) {
    int wave  = (blockIdx.x * blockDim.x + threadIdx.x) >> 6;
    int lane  = threadIdx.x & 63;
    int nwave = (gridDim.x * blockDim.x) >> 6;
    int n4 = size >> 2;
    for (int row = wave; row < size; row += nwave) {
        const float4* g = (const float4*)(G_gap + (size_t)row * size);
        float acc = 0.f;
        for (int k = lane; k < n4; k += 64) {
            float4 a = g[k];
            acc += a.x + a.y + a.z + a.w;
        }
        acc = wave_reduce(acc);
        if (lane == 0) co_gap[row] = acc;
    }
}

__global__ void k_step(const float* __restrict__ G_syn, const float* __restrict__ G_gap,
                       const float* __restrict__ G_leak, const float* __restrict__ E_leak,
                       const float* __restrict__ E_syn, const float* __restrict__ co_gap,
                       float* __restrict__ Vb, float* __restrict__ sb, float* __restrict__ sEb,
                       int size, int nsteps, float dt) {
    cg::grid_group grid = cg::this_grid();
    int wave  = (blockIdx.x * blockDim.x + threadIdx.x) >> 6;
    int lane  = threadIdx.x & 63;
    int nwave = (gridDim.x * blockDim.x) >> 6;
    int n4 = size >> 2;
    int cur = 0;
    for (int t = 0; t < nsteps; ++t) {
        const float* Vc  = Vb  + (size_t)cur * size;
        const float* sc  = sb  + (size_t)cur * size;
        const float* sEc = sEb + (size_t)cur * size;
        float* Vn  = Vb  + (size_t)(cur ^ 1) * size;
        float* sn  = sb  + (size_t)(cur ^ 1) * size;
        float* sEn = sEb + (size_t)(cur ^ 1) * size;

        for (int row = wave; row < size; row += nwave) {
            const float4* gs  = (const float4*)(G_syn + (size_t)row * size);
            const float4* gg  = (const float4*)(G_gap + (size_t)row * size);
            const float4* s4  = (const float4*)sc;
            const float4* sE4 = (const float4*)sEc;
            const float4* V4  = (const float4*)Vc;
            float cs = 0.f, isn = 0.f, igp = 0.f;
            for (int k = lane; k < n4; k += 64) {
                float4 g  = gs[k];
                float4 sj = s4[k];
                float4 ej = sE4[k];
                cs  += g.x * sj.x + g.y * sj.y + g.z * sj.z + g.w * sj.w;
                isn += g.x * ej.x + g.y * ej.y + g.z * ej.z + g.w * ej.w;
                float4 h  = gg[k];
                float4 vj = V4[k];
                igp += h.x * vj.x + h.y * vj.y + h.z * vj.z + h.w * vj.w;
            }
            cs  = wave_reduce(cs);
            isn = wave_reduce(isn);
            igp = wave_reduce(igp);
            if (lane == 0) {
                float V = Vc[row], s = sc[row];
                float gl = G_leak[row], el = E_leak[row], cgp = co_gap[row];
                float I_leak = gl * (V - el);
                float I_syn  = V * cs - isn;
                float I_gap  = V * cgp - igp;
                float dV = -(I_leak + I_syn + I_gap);
                float sig = 1.f / (1.f + expf(-(BETA * (V - V_TH))));
                float ds = A_R * sig * (1.f - s) - A_D * s;
                float V_inf = (gl * el + isn + igp) / (gl + cs + cgp);
                float diff = fabsf(V_inf - V);
                float vs = dV * dt;
                vs = fminf(fmaxf(vs, -diff), diff);
                float Vnew = V + vs;
                float snew = s + ds * dt;
                Vn[row]  = Vnew;
                sn[row]  = snew;
                sEn[row] = snew * E_syn[row];
            }
        }
        grid.sync();
        cur ^= 1;
    }
}

__global__ void k_out(const float* __restrict__ V, int in_len, int size, float* __restrict__ out) {
    int i = blockIdx.x * blockDim.x + threadIdx.x;
    if (i < size) out[i] = (i < in_len) ? V[i] : 0.f;
}

extern "C" void kernel_launch(void* const* d_in, const int* in_sizes, int n_in,
                              void* d_out, int out_size, void* d_ws, size_t ws_size,
                              hipStream_t stream) {
    const float* input_V = (const float*)d_in[0];
    const float* G_leak  = (const float*)d_in[1];
    const float* E_leak  = (const float*)d_in[2];
    const float* G_syn   = (const float*)d_in[3];
    const float* E_syn   = (const float*)d_in[4];
    const float* G_gap   = (const float*)d_in[5];
    // d_in[6] = timestep (0.1, static), d_in[7] = runtime (30.0, static)

    int in_len = in_sizes[0];
    int size   = in_sizes[1];

    // Replicate the reference's Python-float step count exactly (IEEE double).
    double t = 0.0;
    int nsteps = 0;
    while (t < 30.0) { t += 0.1; ++nsteps; }
    float dt = 0.1f;  // float32(0.1), as jnp.asarray(timestep, float32)

    float* ws     = (float*)d_ws;
    float* Vb     = ws;                       // 2*size (double buffer)
    float* sb     = ws + 2 * (size_t)size;    // 2*size
    float* sEb    = ws + 4 * (size_t)size;    // 2*size
    float* co_gap = ws + 6 * (size_t)size;    // size
    float* avg    = ws + 7 * (size_t)size;    // 1

    k_mean<<<1, 256, 0, stream>>>(input_V, in_len, avg);
    k_init<<<(size + 255) / 256, 256, 0, stream>>>(input_V, E_syn, avg, in_len, size, Vb, sb, sEb);
    k_cogap<<<512, 256, 0, stream>>>(G_gap, size, co_gap);

    dim3 grid(512), block(256);
    void* args[] = {(void*)&G_syn, (void*)&G_gap, (void*)&G_leak, (void*)&E_leak,
                    (void*)&E_syn, (void*)&co_gap, (void*)&Vb, (void*)&sb, (void*)&sEb,
                    (void*)&size, (void*)&nsteps, (void*)&dt};
    hipLaunchCooperativeKernel((void*)k_step, grid, block, args, 0, stream);

    const float* Vfinal = Vb + (size_t)(nsteps & 1) * size;
    k_out<<<(size + 255) / 256, 256, 0, stream>>>(Vfinal, in_len, size, (float*)d_out);
}

// Round 4
// 6266.754 us; speedup vs baseline: 3.9709x; 3.9709x over previous
//
#include <hip/hip_runtime.h>

#define BETA 0.125f
#define V_TH (-15.0f)
#define A_R 1.0f
#define A_D 5.0f

__device__ __forceinline__ float wave_reduce(float v) {
    #pragma unroll
    for (int off = 32; off > 0; off >>= 1) v += __shfl_xor(v, off, 64);
    return v;
}

__device__ __forceinline__ float dot4(const float4 a, const float4 b) {
    return a.x * b.x + a.y * b.y + a.z * b.z + a.w * b.w;
}

__global__ void k_mean(const float* __restrict__ in, int n, float* __restrict__ out) {
    __shared__ float partial[4];
    int tid = threadIdx.x;
    float acc = 0.f;
    for (int i = tid; i < n; i += 256) acc += in[i];
    acc = wave_reduce(acc);
    int wid = tid >> 6;
    if ((tid & 63) == 0) partial[wid] = acc;
    __syncthreads();
    if (tid == 0) out[0] = (partial[0] + partial[1] + partial[2] + partial[3]) / (float)n;
}

__global__ void k_init(const float* __restrict__ input_V, const float* __restrict__ E_syn,
                       const float* __restrict__ avg, int in_len, int size,
                       float* __restrict__ V, float* __restrict__ s, float* __restrict__ sE) {
    int i = blockIdx.x * blockDim.x + threadIdx.x;
    if (i >= size) return;
    float v = (i < in_len) ? input_V[i] : avg[0];
    float sig = 1.f / (1.f + expf(-(BETA * (v - V_TH))));
    float s0 = A_R * sig / (A_R * sig + A_D);
    V[i] = v;
    s[i] = s0;
    sE[i] = s0 * E_syn[i];
}

__global__ void k_cogap(const float* __restrict__ G_gap, int size, float* __restrict__ co_gap) {
    int wave  = (blockIdx.x * blockDim.x + threadIdx.x) >> 6;
    int lane  = threadIdx.x & 63;
    int nwave = (gridDim.x * blockDim.x) >> 6;
    int n4 = size >> 2;
    for (int row = wave; row < size; row += nwave) {
        const float4* g = (const float4*)(G_gap + (size_t)row * size);
        float acc = 0.f;
        for (int k = lane; k < n4; k += 64) {
            float4 a = g[k];
            acc += a.x + a.y + a.z + a.w;
        }
        acc = wave_reduce(acc);
        if (lane == 0) co_gap[row] = acc;
    }
}

// One block (256 threads) per row. One launch per timestep: stream ordering is
// the inter-step barrier -> no cooperative launch, no co-residency assumptions.
__global__ void k_step1(const float* __restrict__ G_syn, const float* __restrict__ G_gap,
                        const float* __restrict__ G_leak, const float* __restrict__ E_leak,
                        const float* __restrict__ E_syn, const float* __restrict__ co_gap,
                        const float* __restrict__ Vc, const float* __restrict__ sc,
                        const float* __restrict__ sEc,
                        float* __restrict__ Vn, float* __restrict__ sn,
                        float* __restrict__ sEn,
                        int size, float dt) {
    __shared__ float part[4][3];
    int row  = blockIdx.x;
    int tid  = threadIdx.x;
    int lane = tid & 63;
    int wid  = tid >> 6;
    int n4   = size >> 2;

    const float4* gs = (const float4*)(G_syn + (size_t)row * size);
    const float4* gg = (const float4*)(G_gap + (size_t)row * size);
    const float4* s4 = (const float4*)sc;
    const float4* e4 = (const float4*)sEc;
    const float4* v4 = (const float4*)Vc;

    float cs = 0.f, isn = 0.f, igp = 0.f;
    int k0 = tid;
    // For size=4096: n4=1024, each thread does exactly one batched iteration
    // covering k0, k0+256, k0+512, k0+768 -> the whole row is in flight at once.
    for (; k0 + 768 < n4; k0 += 1024) {
        float4 p0 = gs[k0];
        float4 p1 = gs[k0 + 256];
        float4 p2 = gs[k0 + 512];
        float4 p3 = gs[k0 + 768];
        float4 q0 = gg[k0];
        float4 q1 = gg[k0 + 256];
        float4 q2 = gg[k0 + 512];
        float4 q3 = gg[k0 + 768];
        float4 a0 = s4[k0];
        float4 a1 = s4[k0 + 256];
        float4 a2 = s4[k0 + 512];
        float4 a3 = s4[k0 + 768];
        float4 b0 = e4[k0];
        float4 b1 = e4[k0 + 256];
        float4 b2 = e4[k0 + 512];
        float4 b3 = e4[k0 + 768];
        float4 c0 = v4[k0];
        float4 c1 = v4[k0 + 256];
        float4 c2 = v4[k0 + 512];
        float4 c3 = v4[k0 + 768];
        cs += dot4(p0, a0); isn += dot4(p0, b0); igp += dot4(q0, c0);
        cs += dot4(p1, a1); isn += dot4(p1, b1); igp += dot4(q1, c1);
        cs += dot4(p2, a2); isn += dot4(p2, b2); igp += dot4(q2, c2);
        cs += dot4(p3, a3); isn += dot4(p3, b3); igp += dot4(q3, c3);
    }
    for (; k0 < n4; k0 += 256) {
        float4 p = gs[k0];
        float4 q = gg[k0];
        float4 a = s4[k0];
        float4 b = e4[k0];
        float4 c = v4[k0];
        cs += dot4(p, a); isn += dot4(p, b); igp += dot4(q, c);
    }

    cs  = wave_reduce(cs);
    isn = wave_reduce(isn);
    igp = wave_reduce(igp);
    if (lane == 0) {
        part[wid][0] = cs;
        part[wid][1] = isn;
        part[wid][2] = igp;
    }
    __syncthreads();
    if (tid == 0) {
        float CS  = part[0][0] + part[1][0] + part[2][0] + part[3][0];
        float ISN = part[0][1] + part[1][1] + part[2][1] + part[3][1];
        float IGP = part[0][2] + part[1][2] + part[2][2] + part[3][2];
        float V = Vc[row], s = sc[row];
        float gl = G_leak[row], el = E_leak[row], cgp = co_gap[row];
        float dV = -(gl * (V - el) + (V * CS - ISN) + (V * cgp - IGP));
        float sig = 1.f / (1.f + expf(-(BETA * (V - V_TH))));
        float ds = A_R * sig * (1.f - s) - A_D * s;
        float V_inf = (gl * el + ISN + IGP) / (gl + CS + cgp);
        float diff = fabsf(V_inf - V);
        float vs = fminf(fmaxf(dV * dt, -diff), diff);
        float Vnew = V + vs;
        float snew = s + ds * dt;
        Vn[row]  = Vnew;
        sn[row]  = snew;
        sEn[row] = snew * E_syn[row];
    }
}

__global__ void k_out(const float* __restrict__ V, int in_len, int size, float* __restrict__ out) {
    int i = blockIdx.x * blockDim.x + threadIdx.x;
    if (i < size) out[i] = (i < in_len) ? V[i] : 0.f;
}

extern "C" void kernel_launch(void* const* d_in, const int* in_sizes, int n_in,
                              void* d_out, int out_size, void* d_ws, size_t ws_size,
                              hipStream_t stream) {
    const float* input_V = (const float*)d_in[0];
    const float* G_leak  = (const float*)d_in[1];
    const float* E_leak  = (const float*)d_in[2];
    const float* G_syn   = (const float*)d_in[3];
    const float* E_syn   = (const float*)d_in[4];
    const float* G_gap   = (const float*)d_in[5];

    int in_len = in_sizes[0];
    int size   = in_sizes[1];

    // Replicate the reference's Python-float step count exactly (IEEE double).
    double t = 0.0;
    int nsteps = 0;
    while (t < 30.0) { t += 0.1; ++nsteps; }
    float dt = 0.1f;

    float* ws     = (float*)d_ws;
    float* Vb     = ws;                       // 2*size (double buffer)
    float* sb     = ws + 2 * (size_t)size;    // 2*size
    float* sEb    = ws + 4 * (size_t)size;    // 2*size
    float* co_gap = ws + 6 * (size_t)size;    // size
    float* avg    = ws + 7 * (size_t)size;    // 1

    k_mean<<<1, 256, 0, stream>>>(input_V, in_len, avg);
    k_init<<<(size + 255) / 256, 256, 0, stream>>>(input_V, E_syn, avg, in_len, size, Vb, sb, sEb);
    k_cogap<<<512, 256, 0, stream>>>(G_gap, size, co_gap);

    for (int st = 0; st < nsteps; ++st) {
        int cur = st & 1;
        const float* Vc  = Vb  + (size_t)cur * size;
        const float* sc  = sb  + (size_t)cur * size;
        const float* sEc = sEb + (size_t)cur * size;
        float* Vn  = Vb  + (size_t)(cur ^ 1) * size;
        float* sn  = sb  + (size_t)(cur ^ 1) * size;
        float* sEn = sEb + (size_t)(cur ^ 1) * size;
        k_step1<<<size, 256, 0, stream>>>(G_syn, G_gap, G_leak, E_leak, E_syn, co_gap,
                                          Vc, sc, sEc, Vn, sn, sEn, size, dt);
    }

    const float* Vfinal = Vb + (size_t)(nsteps & 1) * size;
    k_out<<<(size + 255) / 256, 256, 0, stream>>>(Vfinal, in_len, size, (float*)d_out);
}

// Round 5
// 4599.623 us; speedup vs baseline: 5.4102x; 1.3624x over previous
//
#include <hip/hip_runtime.h>
#include <hip/hip_bf16.h>

#define BETA 0.125f
#define V_TH (-15.0f)
#define A_R 1.0f
#define A_D 5.0f

typedef unsigned short ushort_t;
typedef ushort_t __attribute__((ext_vector_type(8))) ushort8;

__device__ __forceinline__ float wave_reduce(float v) {
    #pragma unroll
    for (int off = 32; off > 0; off >>= 1) v += __shfl_xor(v, off, 64);
    return v;
}

__device__ __forceinline__ float dot4(const float4 a, const float4 b) {
    return a.x * b.x + a.y * b.y + a.z * b.z + a.w * b.w;
}

__device__ __forceinline__ float bf2f(ushort_t u) {
    unsigned int v = ((unsigned int)u) << 16;
    union { unsigned int u; float f; } c;
    c.u = v;
    return c.f;
}

__device__ __forceinline__ ushort_t f2bf(float x) {
    __hip_bfloat16 h = __float2bfloat16(x);  // RNE
    union { __hip_bfloat16 h; ushort_t u; } c;
    c.h = h;
    return c.u;
}

__global__ void k_mean(const float* __restrict__ in, int n, float* __restrict__ out) {
    __shared__ float partial[4];
    int tid = threadIdx.x;
    float acc = 0.f;
    for (int i = tid; i < n; i += 256) acc += in[i];
    acc = wave_reduce(acc);
    int wid = tid >> 6;
    if ((tid & 63) == 0) partial[wid] = acc;
    __syncthreads();
    if (tid == 0) out[0] = (partial[0] + partial[1] + partial[2] + partial[3]) / (float)n;
}

__global__ void k_init(const float* __restrict__ input_V, const float* __restrict__ E_syn,
                       const float* __restrict__ avg, int in_len, int size,
                       float* __restrict__ V, float* __restrict__ s, float* __restrict__ sE) {
    int i = blockIdx.x * blockDim.x + threadIdx.x;
    if (i >= size) return;
    float v = (i < in_len) ? input_V[i] : avg[0];
    float sig = 1.f / (1.f + expf(-(BETA * (v - V_TH))));
    float s0 = A_R * sig / (A_R * sig + A_D);
    V[i] = v;
    s[i] = s0;
    sE[i] = s0 * E_syn[i];
}

__global__ void k_cogap(const float* __restrict__ G_gap, int size, float* __restrict__ co_gap) {
    int wave  = (blockIdx.x * blockDim.x + threadIdx.x) >> 6;
    int lane  = threadIdx.x & 63;
    int nwave = (gridDim.x * blockDim.x) >> 6;
    int n4 = size >> 2;
    for (int row = wave; row < size; row += nwave) {
        const float4* g = (const float4*)(G_gap + (size_t)row * size);
        float acc = 0.f;
        for (int k = lane; k < n4; k += 64) {
            float4 a = g[k];
            acc += a.x + a.y + a.z + a.w;
        }
        acc = wave_reduce(acc);
        if (lane == 0) co_gap[row] = acc;
    }
}

// fp32 -> bf16 (RNE) conversion, 8 elems/thread/iter.
__global__ void k_conv(const float* __restrict__ in, ushort_t* __restrict__ out, size_t n) {
    size_t stride = (size_t)gridDim.x * blockDim.x * 8;
    for (size_t i = ((size_t)blockIdx.x * blockDim.x + threadIdx.x) * 8; i + 7 < n; i += stride) {
        float4 a = *(const float4*)(in + i);
        float4 b = *(const float4*)(in + i + 4);
        ushort8 r;
        r[0] = f2bf(a.x); r[1] = f2bf(a.y); r[2] = f2bf(a.z); r[3] = f2bf(a.w);
        r[4] = f2bf(b.x); r[5] = f2bf(b.y); r[6] = f2bf(b.z); r[7] = f2bf(b.w);
        *(ushort8*)(out + i) = r;
    }
}

// One block (256 threads) per row, bf16 matrices. One launch per timestep.
__global__ void k_step_bf16(const ushort_t* __restrict__ Gs16, const ushort_t* __restrict__ Gg16,
                            const float* __restrict__ G_leak, const float* __restrict__ E_leak,
                            const float* __restrict__ E_syn, const float* __restrict__ co_gap,
                            const float* __restrict__ Vc, const float* __restrict__ sc,
                            const float* __restrict__ sEc,
                            float* __restrict__ Vn, float* __restrict__ sn,
                            float* __restrict__ sEn,
                            int size, float dt) {
    __shared__ float part[4][3];
    int row  = blockIdx.x;
    int tid  = threadIdx.x;
    int lane = tid & 63;
    int wid  = tid >> 6;
    int n8   = size >> 3;

    const ushort8* gs8 = (const ushort8*)(Gs16 + (size_t)row * size);
    const ushort8* gg8 = (const ushort8*)(Gg16 + (size_t)row * size);
    const float4* s4 = (const float4*)sc;
    const float4* e4 = (const float4*)sEc;
    const float4* v4 = (const float4*)Vc;

    float cs = 0.f, isn = 0.f, igp = 0.f;
    int k = tid;
    // size=4096: n8=512, each thread does one dual-chunk iteration
    // (4 ushort8 + 12 float4 loads issued before use).
    for (; k + 256 < n8; k += 512) {
        int k1 = k + 256;
        ushort8 gA = gs8[k];
        ushort8 gB = gs8[k1];
        ushort8 hA = gg8[k];
        ushort8 hB = gg8[k1];
        float4 sA0 = s4[2 * k];
        float4 sA1 = s4[2 * k + 1];
        float4 sB0 = s4[2 * k1];
        float4 sB1 = s4[2 * k1 + 1];
        float4 eA0 = e4[2 * k];
        float4 eA1 = e4[2 * k + 1];
        float4 eB0 = e4[2 * k1];
        float4 eB1 = e4[2 * k1 + 1];
        float4 vA0 = v4[2 * k];
        float4 vA1 = v4[2 * k + 1];
        float4 vB0 = v4[2 * k1];
        float4 vB1 = v4[2 * k1 + 1];
        float4 gA0 = make_float4(bf2f(gA[0]), bf2f(gA[1]), bf2f(gA[2]), bf2f(gA[3]));
        float4 gA1 = make_float4(bf2f(gA[4]), bf2f(gA[5]), bf2f(gA[6]), bf2f(gA[7]));
        float4 gB0 = make_float4(bf2f(gB[0]), bf2f(gB[1]), bf2f(gB[2]), bf2f(gB[3]));
        float4 gB1 = make_float4(bf2f(gB[4]), bf2f(gB[5]), bf2f(gB[6]), bf2f(gB[7]));
        float4 hA0 = make_float4(bf2f(hA[0]), bf2f(hA[1]), bf2f(hA[2]), bf2f(hA[3]));
        float4 hA1 = make_float4(bf2f(hA[4]), bf2f(hA[5]), bf2f(hA[6]), bf2f(hA[7]));
        float4 hB0 = make_float4(bf2f(hB[0]), bf2f(hB[1]), bf2f(hB[2]), bf2f(hB[3]));
        float4 hB1 = make_float4(bf2f(hB[4]), bf2f(hB[5]), bf2f(hB[6]), bf2f(hB[7]));
        cs  += dot4(gA0, sA0); cs  += dot4(gA1, sA1);
        cs  += dot4(gB0, sB0); cs  += dot4(gB1, sB1);
        isn += dot4(gA0, eA0); isn += dot4(gA1, eA1);
        isn += dot4(gB0, eB0); isn += dot4(gB1, eB1);
        igp += dot4(hA0, vA0); igp += dot4(hA1, vA1);
        igp += dot4(hB0, vB0); igp += dot4(hB1, vB1);
    }
    for (; k < n8; k += 256) {
        ushort8 gA = gs8[k];
        ushort8 hA = gg8[k];
        float4 sA0 = s4[2 * k];
        float4 sA1 = s4[2 * k + 1];
        float4 eA0 = e4[2 * k];
        float4 eA1 = e4[2 * k + 1];
        float4 vA0 = v4[2 * k];
        float4 vA1 = v4[2 * k + 1];
        float4 gA0 = make_float4(bf2f(gA[0]), bf2f(gA[1]), bf2f(gA[2]), bf2f(gA[3]));
        float4 gA1 = make_float4(bf2f(gA[4]), bf2f(gA[5]), bf2f(gA[6]), bf2f(gA[7]));
        float4 hA0 = make_float4(bf2f(hA[0]), bf2f(hA[1]), bf2f(hA[2]), bf2f(hA[3]));
        float4 hA1 = make_float4(bf2f(hA[4]), bf2f(hA[5]), bf2f(hA[6]), bf2f(hA[7]));
        cs  += dot4(gA0, sA0); cs  += dot4(gA1, sA1);
        isn += dot4(gA0, eA0); isn += dot4(gA1, eA1);
        igp += dot4(hA0, vA0); igp += dot4(hA1, vA1);
    }

    cs  = wave_reduce(cs);
    isn = wave_reduce(isn);
    igp = wave_reduce(igp);
    if (lane == 0) {
        part[wid][0] = cs;
        part[wid][1] = isn;
        part[wid][2] = igp;
    }
    __syncthreads();
    if (tid == 0) {
        float CS  = part[0][0] + part[1][0] + part[2][0] + part[3][0];
        float ISN = part[0][1] + part[1][1] + part[2][1] + part[3][1];
        float IGP = part[0][2] + part[1][2] + part[2][2] + part[3][2];
        float V = Vc[row], s = sc[row];
        float gl = G_leak[row], el = E_leak[row], cgp = co_gap[row];
        float dV = -(gl * (V - el) + (V * CS - ISN) + (V * cgp - IGP));
        float sig = 1.f / (1.f + expf(-(BETA * (V - V_TH))));
        float ds = A_R * sig * (1.f - s) - A_D * s;
        float V_inf = (gl * el + ISN + IGP) / (gl + CS + cgp);
        float diff = fabsf(V_inf - V);
        float vs = fminf(fmaxf(dV * dt, -diff), diff);
        float Vnew = V + vs;
        float snew = s + ds * dt;
        Vn[row]  = Vnew;
        sn[row]  = snew;
        sEn[row] = snew * E_syn[row];
    }
}

// fp32 fallback (R4-proven) in case ws_size can't hold the bf16 matrices.
__global__ void k_step1(const float* __restrict__ G_syn, const float* __restrict__ G_gap,
                        const float* __restrict__ G_leak, const float* __restrict__ E_leak,
                        const float* __restrict__ E_syn, const float* __restrict__ co_gap,
                        const float* __restrict__ Vc, const float* __restrict__ sc,
                        const float* __restrict__ sEc,
                        float* __restrict__ Vn, float* __restrict__ sn,
                        float* __restrict__ sEn,
                        int size, float dt) {
    __shared__ float part[4][3];
    int row  = blockIdx.x;
    int tid  = threadIdx.x;
    int lane = tid & 63;
    int wid  = tid >> 6;
    int n4   = size >> 2;

    const float4* gs = (const float4*)(G_syn + (size_t)row * size);
    const float4* gg = (const float4*)(G_gap + (size_t)row * size);
    const float4* s4 = (const float4*)sc;
    const float4* e4 = (const float4*)sEc;
    const float4* v4 = (const float4*)Vc;

    float cs = 0.f, isn = 0.f, igp = 0.f;
    int k0 = tid;
    for (; k0 + 768 < n4; k0 += 1024) {
        float4 p0 = gs[k0];
        float4 p1 = gs[k0 + 256];
        float4 p2 = gs[k0 + 512];
        float4 p3 = gs[k0 + 768];
        float4 q0 = gg[k0];
        float4 q1 = gg[k0 + 256];
        float4 q2 = gg[k0 + 512];
        float4 q3 = gg[k0 + 768];
        float4 a0 = s4[k0];
        float4 a1 = s4[k0 + 256];
        float4 a2 = s4[k0 + 512];
        float4 a3 = s4[k0 + 768];
        float4 b0 = e4[k0];
        float4 b1 = e4[k0 + 256];
        float4 b2 = e4[k0 + 512];
        float4 b3 = e4[k0 + 768];
        float4 c0 = v4[k0];
        float4 c1 = v4[k0 + 256];
        float4 c2 = v4[k0 + 512];
        float4 c3 = v4[k0 + 768];
        cs += dot4(p0, a0); isn += dot4(p0, b0); igp += dot4(q0, c0);
        cs += dot4(p1, a1); isn += dot4(p1, b1); igp += dot4(q1, c1);
        cs += dot4(p2, a2); isn += dot4(p2, b2); igp += dot4(q2, c2);
        cs += dot4(p3, a3); isn += dot4(p3, b3); igp += dot4(q3, c3);
    }
    for (; k0 < n4; k0 += 256) {
        float4 p = gs[k0];
        float4 q = gg[k0];
        float4 a = s4[k0];
        float4 b = e4[k0];
        float4 c = v4[k0];
        cs += dot4(p, a); isn += dot4(p, b); igp += dot4(q, c);
    }

    cs  = wave_reduce(cs);
    isn = wave_reduce(isn);
    igp = wave_reduce(igp);
    if (lane == 0) {
        part[wid][0] = cs;
        part[wid][1] = isn;
        part[wid][2] = igp;
    }
    __syncthreads();
    if (tid == 0) {
        float CS  = part[0][0] + part[1][0] + part[2][0] + part[3][0];
        float ISN = part[0][1] + part[1][1] + part[2][1] + part[3][1];
        float IGP = part[0][2] + part[1][2] + part[2][2] + part[3][2];
        float V = Vc[row], s = sc[row];
        float gl = G_leak[row], el = E_leak[row], cgp = co_gap[row];
        float dV = -(gl * (V - el) + (V * CS - ISN) + (V * cgp - IGP));
        float sig = 1.f / (1.f + expf(-(BETA * (V - V_TH))));
        float ds = A_R * sig * (1.f - s) - A_D * s;
        float V_inf = (gl * el + ISN + IGP) / (gl + CS + cgp);
        float diff = fabsf(V_inf - V);
        float vs = fminf(fmaxf(dV * dt, -diff), diff);
        float Vnew = V + vs;
        float snew = s + ds * dt;
        Vn[row]  = Vnew;
        sn[row]  = snew;
        sEn[row] = snew * E_syn[row];
    }
}

__global__ void k_out(const float* __restrict__ V, int in_len, int size, float* __restrict__ out) {
    int i = blockIdx.x * blockDim.x + threadIdx.x;
    if (i < size) out[i] = (i < in_len) ? V[i] : 0.f;
}

extern "C" void kernel_launch(void* const* d_in, const int* in_sizes, int n_in,
                              void* d_out, int out_size, void* d_ws, size_t ws_size,
                              hipStream_t stream) {
    const float* input_V = (const float*)d_in[0];
    const float* G_leak  = (const float*)d_in[1];
    const float* E_leak  = (const float*)d_in[2];
    const float* G_syn   = (const float*)d_in[3];
    const float* E_syn   = (const float*)d_in[4];
    const float* G_gap   = (const float*)d_in[5];

    int in_len = in_sizes[0];
    int size   = in_sizes[1];
    size_t NN  = (size_t)size * size;

    // Replicate the reference's Python-float step count exactly (IEEE double).
    double t = 0.0;
    int nsteps = 0;
    while (t < 30.0) { t += 0.1; ++nsteps; }
    float dt = 0.1f;

    // bf16 layout: [Gs16: NN ushort][Gg16: NN ushort][float vectors...]
    size_t vec_floats = 7 * (size_t)size + 4;
    size_t need_bf16  = 4 * NN + vec_floats * sizeof(float);
    bool use_bf16 = (ws_size >= need_bf16);

    if (use_bf16) {
        ushort_t* Gs16 = (ushort_t*)d_ws;
        ushort_t* Gg16 = Gs16 + NN;
        float* fv     = (float*)(Gg16 + NN);
        float* Vb     = fv;
        float* sb     = fv + 2 * (size_t)size;
        float* sEb    = fv + 4 * (size_t)size;
        float* co_gap = fv + 6 * (size_t)size;
        float* avg    = fv + 7 * (size_t)size;

        k_conv<<<2048, 256, 0, stream>>>(G_syn, Gs16, NN);
        k_conv<<<2048, 256, 0, stream>>>(G_gap, Gg16, NN);
        k_mean<<<1, 256, 0, stream>>>(input_V, in_len, avg);
        k_init<<<(size + 255) / 256, 256, 0, stream>>>(input_V, E_syn, avg, in_len, size, Vb, sb, sEb);
        k_cogap<<<512, 256, 0, stream>>>(G_gap, size, co_gap);

        for (int st = 0; st < nsteps; ++st) {
            int cur = st & 1;
            const float* Vc  = Vb  + (size_t)cur * size;
            const float* sc  = sb  + (size_t)cur * size;
            const float* sEc = sEb + (size_t)cur * size;
            float* Vn  = Vb  + (size_t)(cur ^ 1) * size;
            float* sn  = sb  + (size_t)(cur ^ 1) * size;
            float* sEn = sEb + (size_t)(cur ^ 1) * size;
            k_step_bf16<<<size, 256, 0, stream>>>(Gs16, Gg16, G_leak, E_leak, E_syn, co_gap,
                                                  Vc, sc, sEc, Vn, sn, sEn, size, dt);
        }

        const float* Vfinal = Vb + (size_t)(nsteps & 1) * size;
        k_out<<<(size + 255) / 256, 256, 0, stream>>>(Vfinal, in_len, size, (float*)d_out);
    } else {
        float* ws     = (float*)d_ws;
        float* Vb     = ws;
        float* sb     = ws + 2 * (size_t)size;
        float* sEb    = ws + 4 * (size_t)size;
        float* co_gap = ws + 6 * (size_t)size;
        float* avg    = ws + 7 * (size_t)size;

        k_mean<<<1, 256, 0, stream>>>(input_V, in_len, avg);
        k_init<<<(size + 255) / 256, 256, 0, stream>>>(input_V, E_syn, avg, in_len, size, Vb, sb, sEb);
        k_cogap<<<512, 256, 0, stream>>>(G_gap, size, co_gap);

        for (int st = 0; st < nsteps; ++st) {
            int cur = st & 1;
            const float* Vc  = Vb  + (size_t)cur * size;
            const float* sc  = sb  + (size_t)cur * size;
            const float* sEc = sEb + (size_t)cur * size;
            float* Vn  = Vb  + (size_t)(cur ^ 1) * size;
            float* sn  = sb  + (size_t)(cur ^ 1) * size;
            float* sEn = sEb + (size_t)(cur ^ 1) * size;
            k_step1<<<size, 256, 0, stream>>>(G_syn, G_gap, G_leak, E_leak, E_syn, co_gap,
                                              Vc, sc, sEc, Vn, sn, sEn, size, dt);
        }

        const float* Vfinal = Vb + (size_t)(nsteps & 1) * size;
        k_out<<<(size + 255) / 256, 256, 0, stream>>>(Vfinal, in_len, size, (float*)d_out);
    }
}